// Round 5
// baseline (582.005 us; speedup 1.0000x reference)
//
#include <hip/hip_runtime.h>
#include <cstdint>
#include <cstddef>

// ---- sizes (compile-time for this problem) ----
#define S_  1024
#define B_  8
#define D_  1024
#define H_  16
#define HD_ 64
#define DFF_ 4096
#define M_  (S_*B_)      // 8192 rows
#define QKV_N (3*D_)     // 3072

typedef float f32x4 __attribute__((ext_vector_type(4)));
typedef __bf16 bf16x8 __attribute__((ext_vector_type(8)));
typedef __bf16 bf16x4 __attribute__((ext_vector_type(4)));

#define GLDS16(gp, lp) __builtin_amdgcn_global_load_lds( \
    (__attribute__((address_space(1))) void*)(gp), \
    (__attribute__((address_space(3))) void*)(lp), 16, 0, 0)

// ---------------------------------------------------------------------------
// fused fp32 -> bf16 conversion of all 5 tensors in one launch
// ---------------------------------------------------------------------------
#define CB0 (M_*D_/4)
#define CB1 (CB0 + QKV_N*D_/4)
#define CB2 (CB1 + D_*D_/4)
#define CB3 (CB2 + DFF_*D_/4)
#define CB4 (CB3 + D_*DFF_/4)

__global__ __launch_bounds__(256)
void cvt_all(const float* __restrict__ src, const float* __restrict__ w1f,
             const float* __restrict__ w2f, const float* __restrict__ w3f,
             const float* __restrict__ w4f,
             __bf16* __restrict__ src_bf, __bf16* __restrict__ w1,
             __bf16* __restrict__ w2, __bf16* __restrict__ w3,
             __bf16* __restrict__ w4)
{
    int i = blockIdx.x * 256 + threadIdx.x;
    const float* in; __bf16* out; int off;
    if      (i < CB0) { in = src; out = src_bf; off = 0;   }
    else if (i < CB1) { in = w1f; out = w1;     off = CB0; }
    else if (i < CB2) { in = w2f; out = w2;     off = CB1; }
    else if (i < CB3) { in = w3f; out = w3;     off = CB2; }
    else if (i < CB4) { in = w4f; out = w4;     off = CB3; }
    else return;
    int j = i - off;
    float4 v = *(const float4*)(in + (size_t)j * 4);
    __bf16 t[4] = {(__bf16)v.x, (__bf16)v.y, (__bf16)v.z, (__bf16)v.w};
    *(uint2*)(out + (size_t)j * 4) = *(uint2*)t;
}

// ---------------------------------------------------------------------------
// GEMM: C = A[M,K]*W[N,K]^T (+bias). 128x128 tile, BK=32, 256 thr.
// NSPLIT-way K-split via blockIdx.z; partial z writes to Cv[z].
// ---------------------------------------------------------------------------
template<bool OUT_BF16, bool RELU, bool ADD_BIAS, int NSPLIT>
__global__ __launch_bounds__(256)
void gemm_bt(const __bf16* __restrict__ A, const __bf16* __restrict__ W,
             const float* __restrict__ bias,
             void* __restrict__ Cv0, void* __restrict__ Cv1,
             void* __restrict__ Cv2, void* __restrict__ Cv3,
             int M, int N, int Kloop, int lda)
{
    __shared__ __bf16 As[128 * 32];
    __shared__ __bf16 Bs[128 * 32];

    const int tid  = threadIdx.x;
    const int lane = tid & 63;
    const int wv   = tid >> 6;
    const int quad = lane >> 4;
    const int l15  = lane & 15;
    const int m0 = blockIdx.x * 128;
    const int n0 = blockIdx.y * 128;
    const int wm = (wv >> 1) * 64;
    const int wn = (wv & 1) * 64;

    void* Cv = Cv0;
    if (NSPLIT > 1) {
        const int z = blockIdx.z;
        const int koff = z * Kloop;
        A += koff;
        W += koff;
        Cv = (z == 0) ? Cv0 : (z == 1) ? Cv1 : (z == 2) ? Cv2 : Cv3;
    }

    f32x4 acc[4][4] = {};

    for (int k0 = 0; k0 < Kloop; k0 += 32) {
        __syncthreads();
        #pragma unroll
        for (int j = 0; j < 2; ++j) {
            int c   = j * 256 + tid;          // 512 chunks of 16B = 8KB tile
            int row = c >> 2;
            int cc  = c & 3;
            GLDS16(A + (size_t)(m0 + row) * lda + k0 + cc * 8, (char*)As + c * 16);
            GLDS16(W + (size_t)(n0 + row) * lda + k0 + cc * 8, (char*)Bs + c * 16);
        }
        __syncthreads();

        bf16x8 af[4], bf[4];
        #pragma unroll
        for (int i = 0; i < 4; ++i)
            af[i] = *(const bf16x8*)(As + (wm + i * 16 + l15) * 32 + quad * 8);
        #pragma unroll
        for (int j = 0; j < 4; ++j)
            bf[j] = *(const bf16x8*)(Bs + (wn + j * 16 + l15) * 32 + quad * 8);
        #pragma unroll
        for (int i = 0; i < 4; ++i)
            #pragma unroll
            for (int j = 0; j < 4; ++j)
                acc[i][j] = __builtin_amdgcn_mfma_f32_16x16x32_bf16(af[i], bf[j], acc[i][j], 0, 0, 0);
    }

    // epilogue: C row = wm + i*16 + quad*4 + r ; col = wn + j*16 + l15
    #pragma unroll
    for (int j = 0; j < 4; ++j) {
        const int col = n0 + wn + j * 16 + l15;
        const float bv = ADD_BIAS ? bias[col] : 0.f;
        #pragma unroll
        for (int i = 0; i < 4; ++i) {
            const int rbase = m0 + wm + i * 16 + quad * 4;
            #pragma unroll
            for (int r = 0; r < 4; ++r) {
                float v = acc[i][j][r] + bv;
                if (RELU) v = fmaxf(v, 0.f);
                if (OUT_BF16)
                    ((__bf16*)Cv)[(size_t)(rbase + r) * N + col] = (__bf16)v;
                else
                    ((float*)Cv)[(size_t)(rbase + r) * N + col] = v;
            }
        }
    }
}

// ---------------------------------------------------------------------------
// V transpose: qkv V-part -> vt[bh][d][t]
// ---------------------------------------------------------------------------
__global__ __launch_bounds__(256)
void v_transpose(const __bf16* __restrict__ qkv, __bf16* __restrict__ vt)
{
    __shared__ __bf16 T[64 * 65];
    const int tid = threadIdx.x;
    const int t0  = blockIdx.x * 64;
    const int bh  = blockIdx.y;
    const int b   = bh & (B_ - 1);
    const int h   = bh / B_;

    #pragma unroll
    for (int j = 0; j < 2; ++j) {
        int c = j * 256 + tid;
        int i = c >> 3, cc = c & 7;
        const __bf16* g = qkv + (size_t)((t0 + i) * B_ + b) * QKV_N + 2 * D_ + h * HD_ + cc * 8;
        bf16x8 v = *(const bf16x8*)g;
        #pragma unroll
        for (int u = 0; u < 8; ++u) T[(cc * 8 + u) * 65 + i] = v[u];
    }
    __syncthreads();
    #pragma unroll
    for (int j = 0; j < 2; ++j) {
        int c = j * 256 + tid;
        int d = c >> 3, cc = c & 7;
        __bf16 pk[8];
        #pragma unroll
        for (int u = 0; u < 8; ++u) pk[u] = T[d * 65 + cc * 8 + u];
        *(uint4*)(vt + ((size_t)bh * HD_ + d) * S_ + t0 + cc * 8) = *(uint4*)pk;
    }
}

// ---------------------------------------------------------------------------
// Flash attention, S^T formulation (round-3; verified).
// ---------------------------------------------------------------------------
#define TST 72

__global__ __launch_bounds__(256)
void attn_flash(const __bf16* __restrict__ qkv, const __bf16* __restrict__ vt,
                __bf16* __restrict__ out)
{
    __shared__ __bf16 Qs[64 * TST];
    __shared__ __bf16 Ks[64 * TST];
    __shared__ __bf16 Vt[64 * TST];
    __shared__ __bf16 Ps[64 * TST];

    const int tid  = threadIdx.x;
    const int lane = tid & 63;
    const int wv   = tid >> 6;
    const int quad = lane >> 4;
    const int l15  = lane & 15;
    const int s0 = blockIdx.x * 64;
    const int bh = blockIdx.y;
    const int b  = bh & (B_ - 1);
    const int h  = bh / B_;

    #pragma unroll
    for (int j = 0; j < 2; ++j) {
        int c = j * 256 + tid;
        int i = c >> 3, cc = c & 7;
        const __bf16* g = qkv + (size_t)((s0 + i) * B_ + b) * QKV_N + h * HD_ + cc * 8;
        *(uint4*)(Qs + i * TST + cc * 8) = *(const uint4*)g;
    }

    f32x4 oacc[4] = {};
    float m_run = -1e30f, l_run = 0.f;
    const float C2    = 0.125f * 1.44269504f;
    const float LOG2E = 1.44269504f;

    for (int t0 = 0; t0 < S_; t0 += 64) {
        __syncthreads();
        #pragma unroll
        for (int j = 0; j < 2; ++j) {
            int c = j * 256 + tid;
            int i = c >> 3, cc = c & 7;
            const __bf16* g = qkv + (size_t)((t0 + i) * B_ + b) * QKV_N + D_ + h * HD_ + cc * 8;
            *(uint4*)(Ks + i * TST + cc * 8) = *(const uint4*)g;
        }
        #pragma unroll
        for (int j = 0; j < 2; ++j) {
            int c = j * 256 + tid;
            int d = c >> 3, cc = c & 7;
            const __bf16* g = vt + ((size_t)bh * HD_ + d) * S_ + t0 + cc * 8;
            *(uint4*)(Vt + d * TST + cc * 8) = *(const uint4*)g;
        }
        __syncthreads();

        f32x4 sacc[4] = {};
        #pragma unroll
        for (int kk = 0; kk < 2; ++kk) {
            bf16x8 bq = *(const bf16x8*)(Qs + (wv * 16 + l15) * TST + kk * 32 + quad * 8);
            #pragma unroll
            for (int j = 0; j < 4; ++j) {
                bf16x8 ak = *(const bf16x8*)(Ks + (j * 16 + l15) * TST + kk * 32 + quad * 8);
                sacc[j] = __builtin_amdgcn_mfma_f32_16x16x32_bf16(ak, bq, sacc[j], 0, 0, 0);
            }
        }

        float mx = sacc[0][0];
        #pragma unroll
        for (int j = 0; j < 4; ++j)
            #pragma unroll
            for (int r = 0; r < 4; ++r) mx = fmaxf(mx, sacc[j][r]);
        mx = fmaxf(mx, __shfl_xor(mx, 16, 64));
        mx = fmaxf(mx, __shfl_xor(mx, 32, 64));
        float mnew = fmaxf(m_run, mx * 0.125f);
        float k1 = mnew * LOG2E;
        float rs = 0.f;
        #pragma unroll
        for (int j = 0; j < 4; ++j)
            #pragma unroll
            for (int r = 0; r < 4; ++r) {
                float p = __builtin_amdgcn_exp2f(sacc[j][r] * C2 - k1);
                sacc[j][r] = p;
                rs += p;
            }
        rs += __shfl_xor(rs, 16, 64);
        rs += __shfl_xor(rs, 32, 64);
        float alpha = __builtin_amdgcn_exp2f((m_run - mnew) * LOG2E);
        l_run = l_run * alpha + rs;
        m_run = mnew;

        #pragma unroll
        for (int j = 0; j < 4; ++j) {
            __bf16 pk[4] = {(__bf16)sacc[j][0], (__bf16)sacc[j][1],
                            (__bf16)sacc[j][2], (__bf16)sacc[j][3]};
            *(uint2*)(Ps + (wv * 16 + l15) * TST + j * 16 + quad * 4) = *(uint2*)pk;
        }

        #pragma unroll
        for (int r = 0; r < 4; ++r) {
            float ar = __shfl(alpha, quad * 4 + r, 64);
            #pragma unroll
            for (int jd = 0; jd < 4; ++jd) oacc[jd][r] *= ar;
        }

        #pragma unroll
        for (int kk = 0; kk < 2; ++kk) {
            bf16x8 ap = *(const bf16x8*)(Ps + (wv * 16 + l15) * TST + kk * 32 + quad * 8);
            #pragma unroll
            for (int jd = 0; jd < 4; ++jd) {
                bf16x8 bv = *(const bf16x8*)(Vt + (jd * 16 + l15) * TST + kk * 32 + quad * 8);
                oacc[jd] = __builtin_amdgcn_mfma_f32_16x16x32_bf16(ap, bv, oacc[jd], 0, 0, 0);
            }
        }
    }

    float linv = 1.f / l_run;
    #pragma unroll
    for (int r = 0; r < 4; ++r) {
        float lr = __shfl(linv, quad * 4 + r, 64);
        int s = s0 + wv * 16 + quad * 4 + r;
        #pragma unroll
        for (int jd = 0; jd < 4; ++jd) {
            int d = jd * 16 + l15;
            out[(size_t)(s * B_ + b) * D_ + h * HD_ + d] = (__bf16)(oacc[jd][r] * lr);
        }
    }
}

// ---------------------------------------------------------------------------
// LayerNorm( xa + p0+p1+p2+p3 + bias[col] ) * g + beta -> yout fp32 (+ybf)
// xa fp32; p0..p3 bf16 split-K partials. One row per 256-thread block.
// ---------------------------------------------------------------------------
__global__ __launch_bounds__(256)
void ln_res4(const float* __restrict__ xa,
             const __bf16* __restrict__ p0, const __bf16* __restrict__ p1,
             const __bf16* __restrict__ p2, const __bf16* __restrict__ p3,
             const float* __restrict__ bias,
             const float* __restrict__ g, const float* __restrict__ beta,
             float* __restrict__ yout, __bf16* __restrict__ ybf)
{
    __shared__ float red[8];
    const int row = blockIdx.x;
    const int tid = threadIdx.x;
    const size_t base = (size_t)row * D_ + tid * 4;

    float4 a  = *(const float4*)(xa + base);
    bf16x4 q0 = *(const bf16x4*)(p0 + base);
    bf16x4 q1 = *(const bf16x4*)(p1 + base);
    bf16x4 q2 = *(const bf16x4*)(p2 + base);
    bf16x4 q3 = *(const bf16x4*)(p3 + base);
    float4 bb = *(const float4*)(bias + tid * 4);
    float x0 = a.x + ((float)q0[0] + (float)q1[0]) + ((float)q2[0] + (float)q3[0]) + bb.x;
    float x1 = a.y + ((float)q0[1] + (float)q1[1]) + ((float)q2[1] + (float)q3[1]) + bb.y;
    float x2 = a.z + ((float)q0[2] + (float)q1[2]) + ((float)q2[2] + (float)q3[2]) + bb.z;
    float x3 = a.w + ((float)q0[3] + (float)q1[3]) + ((float)q2[3] + (float)q3[3]) + bb.w;

    float s  = x0 + x1 + x2 + x3;
    float ss = x0 * x0 + x1 * x1 + x2 * x2 + x3 * x3;
    for (int msk = 1; msk <= 32; msk <<= 1) {
        s  += __shfl_xor(s,  msk, 64);
        ss += __shfl_xor(ss, msk, 64);
    }
    const int wv = tid >> 6;
    if ((tid & 63) == 0) { red[wv] = s; red[4 + wv] = ss; }
    __syncthreads();
    s  = red[0] + red[1] + red[2] + red[3];
    ss = red[4] + red[5] + red[6] + red[7];
    float mean = s * (1.f / D_);
    float var  = ss * (1.f / D_) - mean * mean;
    float rstd = rsqrtf(var + 1e-5f);

    float4 gv = *(const float4*)(g + tid * 4);
    float4 bv = *(const float4*)(beta + tid * 4);
    float y0 = (x0 - mean) * rstd * gv.x + bv.x;
    float y1 = (x1 - mean) * rstd * gv.y + bv.y;
    float y2 = (x2 - mean) * rstd * gv.z + bv.z;
    float y3 = (x3 - mean) * rstd * gv.w + bv.w;
    *(float4*)(yout + base) = make_float4(y0, y1, y2, y3);
    if (ybf) {
        __bf16 t[4] = {(__bf16)y0, (__bf16)y1, (__bf16)y2, (__bf16)y3};
        *(uint2*)(ybf + base) = *(uint2*)t;
    }
}

// ---------------------------------------------------------------------------
extern "C" void kernel_launch(void* const* d_in, const int* in_sizes, int n_in,
                              void* d_out, int out_size, void* d_ws, size_t ws_size,
                              hipStream_t stream)
{
    const float* src       = (const float*)d_in[0];
    const float* in_proj_w = (const float*)d_in[1];
    const float* in_proj_b = (const float*)d_in[2];
    const float* out_w     = (const float*)d_in[3];
    const float* out_b     = (const float*)d_in[4];
    const float* lin1_w    = (const float*)d_in[5];
    const float* lin1_b    = (const float*)d_in[6];
    const float* lin2_w    = (const float*)d_in[7];
    const float* lin2_b    = (const float*)d_in[8];
    const float* n1_g = (const float*)d_in[9];
    const float* n1_b = (const float*)d_in[10];
    const float* n2_g = (const float*)d_in[11];
    const float* n2_b = (const float*)d_in[12];

    char* ws = (char*)d_ws;
    size_t off = 0;
    auto alloc = [&](size_t bytes) { char* p = ws + off; off += (bytes + 255) & ~(size_t)255; return p; };

    __bf16* src_bf = (__bf16*)alloc((size_t)M_ * D_ * 2);      // -> attn_o after QKV GEMM
    __bf16* w1     = (__bf16*)alloc((size_t)QKV_N * D_ * 2);
    __bf16* w2     = (__bf16*)alloc((size_t)D_ * D_ * 2);
    __bf16* w3     = (__bf16*)alloc((size_t)DFF_ * D_ * 2);
    __bf16* w4     = (__bf16*)alloc((size_t)D_ * DFF_ * 2);
    __bf16* qkv    = (__bf16*)alloc((size_t)M_ * QKV_N * 2);   // 48MB; f2,f3 after attn
    char*   h_r    = alloc((size_t)M_ * DFF_ * 2);             // 64MB: o0..o3, then hbf
    __bf16* xbf    = (__bf16*)alloc((size_t)M_ * D_ * 2);      // x bf16; -> f1 after lin1
    float*  xf     = (float*)alloc((size_t)M_ * D_ * 4);
    __bf16* vt     = (__bf16*)alloc((size_t)B_ * H_ * HD_ * S_ * 2); // 16MB; -> f0 after attn

    const size_t PART = (size_t)M_ * D_;   // 8M elems = 16MB bf16
    __bf16* attn_o = src_bf;               // src_bf dead after QKV GEMM
    __bf16* o0 = (__bf16*)h_r;             // outproj partials (die at LN1)
    __bf16* o1 = o0 + PART;
    __bf16* o2 = o1 + PART;
    __bf16* o3 = o2 + PART;
    __bf16* hbf = (__bf16*)h_r;            // lin1 out (after LN1)
    __bf16* f0 = vt;                       // lin2 partials
    __bf16* f1 = xbf;                      // xbf dead after lin1
    __bf16* f2 = qkv;                      // qkv dead after attn
    __bf16* f3 = qkv + PART;

    // 1) all fp32->bf16 conversions
    cvt_all<<<(CB4 + 255) / 256, 256, 0, stream>>>(
        src, in_proj_w, out_w, lin1_w, lin2_w, src_bf, w1, w2, w3, w4);

    // 2) QKV projection: qkv = src*W1^T + b   [8192,3072] bf16
    gemm_bt<true, false, true, 1><<<dim3(M_ / 128, QKV_N / 128), 256, 0, stream>>>(
        src_bf, w1, in_proj_b, qkv, nullptr, nullptr, nullptr, M_, QKV_N, D_, D_);

    // 3) V transpose -> vt[bh][d][t]
    v_transpose<<<dim3(S_ / 64, B_ * H_), 256, 0, stream>>>(qkv, vt);

    // 4) attention -> attn_o bf16
    attn_flash<<<dim3(S_ / 64, B_ * H_), 256, 0, stream>>>(qkv, vt, attn_o);

    // 5) out projection, split-K x4 (Kloop=256): o0..o3 bf16 partials
    gemm_bt<true, false, false, 4><<<dim3(M_ / 128, D_ / 128, 4), 256, 0, stream>>>(
        attn_o, w2, nullptr, o0, o1, o2, o3, M_, D_, D_ / 4, D_);

    // 6) x = LN(src + Σo + out_b) -> xf fp32, xbf bf16
    ln_res4<<<M_, 256, 0, stream>>>(src, o0, o1, o2, o3, out_b, n1_g, n1_b, xf, xbf);

    // 7) h = relu(x*W3^T + b3)  bf16 [8192,4096]
    gemm_bt<true, true, true, 1><<<dim3(M_ / 128, DFF_ / 128), 256, 0, stream>>>(
        xbf, w3, lin1_b, hbf, nullptr, nullptr, nullptr, M_, DFF_, D_, D_);

    // 8) lin2, split-K x4 (Kloop=1024): f0..f3 bf16 partials
    gemm_bt<true, false, false, 4><<<dim3(M_ / 128, D_ / 128, 4), 256, 0, stream>>>(
        hbf, w4, nullptr, f0, f1, f2, f3, M_, D_, DFF_ / 4, DFF_);

    // 9) out = LN(xf + Σf + lin2_b)  fp32
    ln_res4<<<M_, 256, 0, stream>>>(xf, f0, f1, f2, f3, lin2_b, n2_g, n2_b, (float*)d_out, nullptr);
}

// Round 6
// 540.567 us; speedup vs baseline: 1.0767x; 1.0767x over previous
//
#include <hip/hip_runtime.h>
#include <cstdint>
#include <cstddef>

// ---- sizes (compile-time for this problem) ----
#define S_  1024
#define B_  8
#define D_  1024
#define H_  16
#define HD_ 64
#define DFF_ 4096
#define M_  (S_*B_)      // 8192 rows
#define QKV_N (3*D_)     // 3072

typedef float f32x4 __attribute__((ext_vector_type(4)));
typedef __bf16 bf16x8 __attribute__((ext_vector_type(8)));
typedef __bf16 bf16x4 __attribute__((ext_vector_type(4)));

#define GLDS16(gp, lp) __builtin_amdgcn_global_load_lds( \
    (__attribute__((address_space(1))) void*)(gp), \
    (__attribute__((address_space(3))) void*)(lp), 16, 0, 0)

// ---------------------------------------------------------------------------
// fused fp32 -> bf16 conversion of all 5 tensors in one launch
// ---------------------------------------------------------------------------
#define CB0 (M_*D_/4)
#define CB1 (CB0 + QKV_N*D_/4)
#define CB2 (CB1 + D_*D_/4)
#define CB3 (CB2 + DFF_*D_/4)
#define CB4 (CB3 + D_*DFF_/4)

__global__ __launch_bounds__(256)
void cvt_all(const float* __restrict__ src, const float* __restrict__ w1f,
             const float* __restrict__ w2f, const float* __restrict__ w3f,
             const float* __restrict__ w4f,
             __bf16* __restrict__ src_bf, __bf16* __restrict__ w1,
             __bf16* __restrict__ w2, __bf16* __restrict__ w3,
             __bf16* __restrict__ w4)
{
    int i = blockIdx.x * 256 + threadIdx.x;
    const float* in; __bf16* out; int off;
    if      (i < CB0) { in = src; out = src_bf; off = 0;   }
    else if (i < CB1) { in = w1f; out = w1;     off = CB0; }
    else if (i < CB2) { in = w2f; out = w2;     off = CB1; }
    else if (i < CB3) { in = w3f; out = w3;     off = CB2; }
    else if (i < CB4) { in = w4f; out = w4;     off = CB3; }
    else return;
    int j = i - off;
    float4 v = *(const float4*)(in + (size_t)j * 4);
    __bf16 t[4] = {(__bf16)v.x, (__bf16)v.y, (__bf16)v.z, (__bf16)v.w};
    *(uint2*)(out + (size_t)j * 4) = *(uint2*)t;
}

// ---------------------------------------------------------------------------
// GEMM: C = A[M,K]*W[N,K]^T (+bias). 128x128 tile, BK=64 (two stacked
// 128x32 panels so GLDS16 stays contiguous and LDS reads keep the 64B-stride
// 2-way-free bank pattern). 256 thr (4 waves, 2x2 of 64x64).
// SPLITZ: blockIdx.z in {0,1} picks K-half and output buffer.
// ---------------------------------------------------------------------------
template<bool OUT_BF16, bool RELU, bool ADD_BIAS, bool SPLITZ>
__global__ __launch_bounds__(256)
void gemm_bt(const __bf16* __restrict__ A, const __bf16* __restrict__ W,
             const float* __restrict__ bias,
             void* __restrict__ Cv0, void* __restrict__ Cv1,
             int M, int N, int Kloop, int lda)
{
    __shared__ __bf16 As[128 * 64];   // two 128x32 panels: [p][row][32]
    __shared__ __bf16 Bs[128 * 64];

    const int tid  = threadIdx.x;
    const int lane = tid & 63;
    const int wv   = tid >> 6;
    const int quad = lane >> 4;
    const int l15  = lane & 15;
    const int m0 = blockIdx.x * 128;
    const int n0 = blockIdx.y * 128;
    const int wm = (wv >> 1) * 64;
    const int wn = (wv & 1) * 64;

    void* Cv = Cv0;
    if (SPLITZ) {
        const int koff = blockIdx.z * Kloop;
        A += koff;
        W += koff;
        if (blockIdx.z) Cv = Cv1;
    }

    f32x4 acc[4][4] = {};

    for (int k0 = 0; k0 < Kloop; k0 += 64) {
        __syncthreads();
        // stage 2 panels x (128x32) per matrix: 1024 chunks of 16B each.
        #pragma unroll
        for (int j = 0; j < 4; ++j) {
            int c   = j * 256 + tid;
            int p   = c >> 9;          // panel (k-half)
            int c2  = c & 511;
            int row = c2 >> 2;
            int cc  = c2 & 3;
            GLDS16(A + (size_t)(m0 + row) * lda + k0 + p * 32 + cc * 8,
                   (char*)As + p * 8192 + c2 * 16);
            GLDS16(W + (size_t)(n0 + row) * lda + k0 + p * 32 + cc * 8,
                   (char*)Bs + p * 8192 + c2 * 16);
        }
        __syncthreads();

        #pragma unroll
        for (int p = 0; p < 2; ++p) {
            bf16x8 af[4], bf[4];
            #pragma unroll
            for (int i = 0; i < 4; ++i)
                af[i] = *(const bf16x8*)(As + p * 4096 + (wm + i * 16 + l15) * 32 + quad * 8);
            #pragma unroll
            for (int j = 0; j < 4; ++j)
                bf[j] = *(const bf16x8*)(Bs + p * 4096 + (wn + j * 16 + l15) * 32 + quad * 8);
            #pragma unroll
            for (int i = 0; i < 4; ++i)
                #pragma unroll
                for (int j = 0; j < 4; ++j)
                    acc[i][j] = __builtin_amdgcn_mfma_f32_16x16x32_bf16(af[i], bf[j], acc[i][j], 0, 0, 0);
        }
    }

    // epilogue: C row = wm + i*16 + quad*4 + r ; col = wn + j*16 + l15
    #pragma unroll
    for (int j = 0; j < 4; ++j) {
        const int col = n0 + wn + j * 16 + l15;
        const float bv = ADD_BIAS ? bias[col] : 0.f;
        #pragma unroll
        for (int i = 0; i < 4; ++i) {
            const int rbase = m0 + wm + i * 16 + quad * 4;
            #pragma unroll
            for (int r = 0; r < 4; ++r) {
                float v = acc[i][j][r] + bv;
                if (RELU) v = fmaxf(v, 0.f);
                if (OUT_BF16)
                    ((__bf16*)Cv)[(size_t)(rbase + r) * N + col] = (__bf16)v;
                else
                    ((float*)Cv)[(size_t)(rbase + r) * N + col] = v;
            }
        }
    }
}

// ---------------------------------------------------------------------------
// V transpose: qkv V-part -> vt[bh][d][t]
// ---------------------------------------------------------------------------
__global__ __launch_bounds__(256)
void v_transpose(const __bf16* __restrict__ qkv, __bf16* __restrict__ vt)
{
    __shared__ __bf16 T[64 * 65];
    const int tid = threadIdx.x;
    const int t0  = blockIdx.x * 64;
    const int bh  = blockIdx.y;
    const int b   = bh & (B_ - 1);
    const int h   = bh / B_;

    #pragma unroll
    for (int j = 0; j < 2; ++j) {
        int c = j * 256 + tid;
        int i = c >> 3, cc = c & 7;
        const __bf16* g = qkv + (size_t)((t0 + i) * B_ + b) * QKV_N + 2 * D_ + h * HD_ + cc * 8;
        bf16x8 v = *(const bf16x8*)g;
        #pragma unroll
        for (int u = 0; u < 8; ++u) T[(cc * 8 + u) * 65 + i] = v[u];
    }
    __syncthreads();
    #pragma unroll
    for (int j = 0; j < 2; ++j) {
        int c = j * 256 + tid;
        int d = c >> 3, cc = c & 7;
        __bf16 pk[8];
        #pragma unroll
        for (int u = 0; u < 8; ++u) pk[u] = T[d * 65 + cc * 8 + u];
        *(uint4*)(vt + ((size_t)bh * HD_ + d) * S_ + t0 + cc * 8) = *(uint4*)pk;
    }
}

// ---------------------------------------------------------------------------
// Flash attention, S^T formulation (round-3; verified).
// ---------------------------------------------------------------------------
#define TST 72

__global__ __launch_bounds__(256)
void attn_flash(const __bf16* __restrict__ qkv, const __bf16* __restrict__ vt,
                __bf16* __restrict__ out)
{
    __shared__ __bf16 Qs[64 * TST];
    __shared__ __bf16 Ks[64 * TST];
    __shared__ __bf16 Vt[64 * TST];
    __shared__ __bf16 Ps[64 * TST];

    const int tid  = threadIdx.x;
    const int lane = tid & 63;
    const int wv   = tid >> 6;
    const int quad = lane >> 4;
    const int l15  = lane & 15;
    const int s0 = blockIdx.x * 64;
    const int bh = blockIdx.y;
    const int b  = bh & (B_ - 1);
    const int h  = bh / B_;

    #pragma unroll
    for (int j = 0; j < 2; ++j) {
        int c = j * 256 + tid;
        int i = c >> 3, cc = c & 7;
        const __bf16* g = qkv + (size_t)((s0 + i) * B_ + b) * QKV_N + h * HD_ + cc * 8;
        *(uint4*)(Qs + i * TST + cc * 8) = *(const uint4*)g;
    }

    f32x4 oacc[4] = {};
    float m_run = -1e30f, l_run = 0.f;
    const float C2    = 0.125f * 1.44269504f;
    const float LOG2E = 1.44269504f;

    for (int t0 = 0; t0 < S_; t0 += 64) {
        __syncthreads();
        #pragma unroll
        for (int j = 0; j < 2; ++j) {
            int c = j * 256 + tid;
            int i = c >> 3, cc = c & 7;
            const __bf16* g = qkv + (size_t)((t0 + i) * B_ + b) * QKV_N + D_ + h * HD_ + cc * 8;
            *(uint4*)(Ks + i * TST + cc * 8) = *(const uint4*)g;
        }
        #pragma unroll
        for (int j = 0; j < 2; ++j) {
            int c = j * 256 + tid;
            int d = c >> 3, cc = c & 7;
            const __bf16* g = vt + ((size_t)bh * HD_ + d) * S_ + t0 + cc * 8;
            *(uint4*)(Vt + d * TST + cc * 8) = *(const uint4*)g;
        }
        __syncthreads();

        f32x4 sacc[4] = {};
        #pragma unroll
        for (int kk = 0; kk < 2; ++kk) {
            bf16x8 bq = *(const bf16x8*)(Qs + (wv * 16 + l15) * TST + kk * 32 + quad * 8);
            #pragma unroll
            for (int j = 0; j < 4; ++j) {
                bf16x8 ak = *(const bf16x8*)(Ks + (j * 16 + l15) * TST + kk * 32 + quad * 8);
                sacc[j] = __builtin_amdgcn_mfma_f32_16x16x32_bf16(ak, bq, sacc[j], 0, 0, 0);
            }
        }

        float mx = sacc[0][0];
        #pragma unroll
        for (int j = 0; j < 4; ++j)
            #pragma unroll
            for (int r = 0; r < 4; ++r) mx = fmaxf(mx, sacc[j][r]);
        mx = fmaxf(mx, __shfl_xor(mx, 16, 64));
        mx = fmaxf(mx, __shfl_xor(mx, 32, 64));
        float mnew = fmaxf(m_run, mx * 0.125f);
        float k1 = mnew * LOG2E;
        float rs = 0.f;
        #pragma unroll
        for (int j = 0; j < 4; ++j)
            #pragma unroll
            for (int r = 0; r < 4; ++r) {
                float p = __builtin_amdgcn_exp2f(sacc[j][r] * C2 - k1);
                sacc[j][r] = p;
                rs += p;
            }
        rs += __shfl_xor(rs, 16, 64);
        rs += __shfl_xor(rs, 32, 64);
        float alpha = __builtin_amdgcn_exp2f((m_run - mnew) * LOG2E);
        l_run = l_run * alpha + rs;
        m_run = mnew;

        #pragma unroll
        for (int j = 0; j < 4; ++j) {
            __bf16 pk[4] = {(__bf16)sacc[j][0], (__bf16)sacc[j][1],
                            (__bf16)sacc[j][2], (__bf16)sacc[j][3]};
            *(uint2*)(Ps + (wv * 16 + l15) * TST + j * 16 + quad * 4) = *(uint2*)pk;
        }

        #pragma unroll
        for (int r = 0; r < 4; ++r) {
            float ar = __shfl(alpha, quad * 4 + r, 64);
            #pragma unroll
            for (int jd = 0; jd < 4; ++jd) oacc[jd][r] *= ar;
        }

        #pragma unroll
        for (int kk = 0; kk < 2; ++kk) {
            bf16x8 ap = *(const bf16x8*)(Ps + (wv * 16 + l15) * TST + kk * 32 + quad * 8);
            #pragma unroll
            for (int jd = 0; jd < 4; ++jd) {
                bf16x8 bv = *(const bf16x8*)(Vt + (jd * 16 + l15) * TST + kk * 32 + quad * 8);
                oacc[jd] = __builtin_amdgcn_mfma_f32_16x16x32_bf16(ap, bv, oacc[jd], 0, 0, 0);
            }
        }
    }

    float linv = 1.f / l_run;
    #pragma unroll
    for (int r = 0; r < 4; ++r) {
        float lr = __shfl(linv, quad * 4 + r, 64);
        int s = s0 + wv * 16 + quad * 4 + r;
        #pragma unroll
        for (int jd = 0; jd < 4; ++jd) {
            int d = jd * 16 + l15;
            out[(size_t)(s * B_ + b) * D_ + h * HD_ + d] = (__bf16)(oacc[jd][r] * lr);
        }
    }
}

// ---------------------------------------------------------------------------
// LayerNorm( xa + p0 + p1 + bias[col] ) * g + beta -> yout fp32 (+ ybf bf16)
// ---------------------------------------------------------------------------
__global__ __launch_bounds__(256)
void ln_res3(const float* __restrict__ xa, const __bf16* __restrict__ p0,
             const __bf16* __restrict__ p1, const float* __restrict__ bias,
             const float* __restrict__ g, const float* __restrict__ beta,
             float* __restrict__ yout, __bf16* __restrict__ ybf)
{
    __shared__ float red[8];
    const int row = blockIdx.x;
    const int tid = threadIdx.x;
    const size_t base = (size_t)row * D_ + tid * 4;

    float4 a  = *(const float4*)(xa + base);
    bf16x4 q0 = *(const bf16x4*)(p0 + base);
    bf16x4 q1 = *(const bf16x4*)(p1 + base);
    float4 bb = *(const float4*)(bias + tid * 4);
    float x0 = a.x + (float)q0[0] + (float)q1[0] + bb.x;
    float x1 = a.y + (float)q0[1] + (float)q1[1] + bb.y;
    float x2 = a.z + (float)q0[2] + (float)q1[2] + bb.z;
    float x3 = a.w + (float)q0[3] + (float)q1[3] + bb.w;

    float s  = x0 + x1 + x2 + x3;
    float ss = x0 * x0 + x1 * x1 + x2 * x2 + x3 * x3;
    for (int msk = 1; msk <= 32; msk <<= 1) {
        s  += __shfl_xor(s,  msk, 64);
        ss += __shfl_xor(ss, msk, 64);
    }
    const int wv = tid >> 6;
    if ((tid & 63) == 0) { red[wv] = s; red[4 + wv] = ss; }
    __syncthreads();
    s  = red[0] + red[1] + red[2] + red[3];
    ss = red[4] + red[5] + red[6] + red[7];
    float mean = s * (1.f / D_);
    float var  = ss * (1.f / D_) - mean * mean;
    float rstd = rsqrtf(var + 1e-5f);

    float4 gv = *(const float4*)(g + tid * 4);
    float4 bv = *(const float4*)(beta + tid * 4);
    float y0 = (x0 - mean) * rstd * gv.x + bv.x;
    float y1 = (x1 - mean) * rstd * gv.y + bv.y;
    float y2 = (x2 - mean) * rstd * gv.z + bv.z;
    float y3 = (x3 - mean) * rstd * gv.w + bv.w;
    *(float4*)(yout + base) = make_float4(y0, y1, y2, y3);
    if (ybf) {
        __bf16 t[4] = {(__bf16)y0, (__bf16)y1, (__bf16)y2, (__bf16)y3};
        *(uint2*)(ybf + base) = *(uint2*)t;
    }
}

// ---------------------------------------------------------------------------
extern "C" void kernel_launch(void* const* d_in, const int* in_sizes, int n_in,
                              void* d_out, int out_size, void* d_ws, size_t ws_size,
                              hipStream_t stream)
{
    const float* src       = (const float*)d_in[0];
    const float* in_proj_w = (const float*)d_in[1];
    const float* in_proj_b = (const float*)d_in[2];
    const float* out_w     = (const float*)d_in[3];
    const float* out_b     = (const float*)d_in[4];
    const float* lin1_w    = (const float*)d_in[5];
    const float* lin1_b    = (const float*)d_in[6];
    const float* lin2_w    = (const float*)d_in[7];
    const float* lin2_b    = (const float*)d_in[8];
    const float* n1_g = (const float*)d_in[9];
    const float* n1_b = (const float*)d_in[10];
    const float* n2_g = (const float*)d_in[11];
    const float* n2_b = (const float*)d_in[12];

    char* ws = (char*)d_ws;
    size_t off = 0;
    auto alloc = [&](size_t bytes) { char* p = ws + off; off += (bytes + 255) & ~(size_t)255; return p; };

    __bf16* src_bf = (__bf16*)alloc((size_t)M_ * D_ * 2);      // -> attn_o after QKV GEMM
    __bf16* w1     = (__bf16*)alloc((size_t)QKV_N * D_ * 2);
    __bf16* w2     = (__bf16*)alloc((size_t)D_ * D_ * 2);
    __bf16* w3     = (__bf16*)alloc((size_t)DFF_ * D_ * 2);
    __bf16* w4     = (__bf16*)alloc((size_t)D_ * DFF_ * 2);
    __bf16* qkv    = (__bf16*)alloc((size_t)M_ * QKV_N * 2);   // 48MB
    char*   h_r    = alloc((size_t)M_ * DFF_ * 2);             // 64MB: o0,o1 then hbf
    __bf16* xbf    = (__bf16*)alloc((size_t)M_ * D_ * 2);      // x bf16; -> f1 after lin1
    float*  xf     = (float*)alloc((size_t)M_ * D_ * 4);
    __bf16* vt     = (__bf16*)alloc((size_t)B_ * H_ * HD_ * S_ * 2); // 16MB; -> f0 after attn

    const size_t PART = (size_t)M_ * D_;   // 8M elems = 16MB bf16
    __bf16* attn_o = src_bf;               // src_bf dead after QKV GEMM
    __bf16* o0 = (__bf16*)h_r;             // outproj split-K partials (die at LN1)
    __bf16* o1 = o0 + PART;
    __bf16* hbf = (__bf16*)h_r;            // lin1 out (after LN1)
    __bf16* f0 = vt;                       // lin2 partials
    __bf16* f1 = xbf;                      // xbf dead after lin1

    // 1) all fp32->bf16 conversions
    cvt_all<<<(CB4 + 255) / 256, 256, 0, stream>>>(
        src, in_proj_w, out_w, lin1_w, lin2_w, src_bf, w1, w2, w3, w4);

    // 2) QKV projection: qkv = src*W1^T + b   [8192,3072] bf16
    gemm_bt<true, false, true, false><<<dim3(M_ / 128, QKV_N / 128), 256, 0, stream>>>(
        src_bf, w1, in_proj_b, qkv, nullptr, M_, QKV_N, D_, D_);

    // 3) V transpose -> vt[bh][d][t]
    v_transpose<<<dim3(S_ / 64, B_ * H_), 256, 0, stream>>>(qkv, vt);

    // 4) attention -> attn_o bf16
    attn_flash<<<dim3(S_ / 64, B_ * H_), 256, 0, stream>>>(qkv, vt, attn_o);

    // 5) out projection, split-K x2 (Kloop=512): o0/o1 bf16 partials
    gemm_bt<true, false, false, true><<<dim3(M_ / 128, D_ / 128, 2), 256, 0, stream>>>(
        attn_o, w2, nullptr, o0, o1, M_, D_, D_ / 2, D_);

    // 6) x = LN(src + o0 + o1 + out_b) -> xf fp32, xbf bf16
    ln_res3<<<M_, 256, 0, stream>>>(src, o0, o1, out_b, n1_g, n1_b, xf, xbf);

    // 7) h = relu(x*W3^T + b3)  bf16 [8192,4096]
    gemm_bt<true, true, true, false><<<dim3(M_ / 128, DFF_ / 128), 256, 0, stream>>>(
        xbf, w3, lin1_b, hbf, nullptr, M_, DFF_, D_, D_);

    // 8) lin2, split-K x2 (Kloop=2048): f0/f1 bf16 partials
    gemm_bt<true, false, false, true><<<dim3(M_ / 128, D_ / 128, 2), 256, 0, stream>>>(
        hbf, w4, nullptr, f0, f1, M_, D_, DFF_ / 2, DFF_);

    // 9) out = LN(xf + f0 + f1 + lin2_b)  fp32
    ln_res3<<<M_, 256, 0, stream>>>(xf, f0, f1, lin2_b, n2_g, n2_b, (float*)d_out, nullptr);
}